// Round 1
// baseline (1188.279 us; speedup 1.0000x reference)
//
#include <hip/hip_runtime.h>
#include <math.h>

#define B_   4
#define N_   2048
#define D_   512
#define DK_  512
#define NH_  8
#define HK_  64
#define SCALE_ 0.125f
#define LN_EPS_ 1e-5f

// ---------------------------------------------------------------------------
// Generic tiled fp32 GEMM: C[M,Nc] = epi(A[M,K] @ Bw[K,Nc] + bias) (+resid)
// 64x64 tile, BK=16, 256 threads, 4x4 register microtile per thread.
// A row-major stride K, Bw row-major stride Nc, C row-major stride Nc.
// epilogue: v += bias[col]; if relu v=max(v,0); v += resid[row*Nc+col]
// ---------------------------------------------------------------------------
__global__ __launch_bounds__(256) void gemm_kernel(
    const float* __restrict__ A, const float* __restrict__ Bw,
    float* __restrict__ C, int M, int Nc, int K,
    const float* __restrict__ bias, const float* __restrict__ resid,
    int do_relu)
{
    __shared__ float As[16][68];  // transposed: As[k][m]
    __shared__ float Bs[16][68];  // Bs[k][n]
    const int tid = threadIdx.x;
    const int tx = tid & 15, ty = tid >> 4;
    const int row0 = ty * 4, col0 = tx * 4;
    const int mt = blockIdx.y * 64, nt = blockIdx.x * 64;

    float acc[4][4] = {};

    for (int kt = 0; kt < K; kt += 16) {
        // stage A tile (64 rows x 16 k), transposed into As[k][m]
        {
            const int r = tid >> 2, kk0 = (tid & 3) << 2;
            const float4 av = *reinterpret_cast<const float4*>(
                &A[(size_t)(mt + r) * K + kt + kk0]);
            As[kk0 + 0][r] = av.x; As[kk0 + 1][r] = av.y;
            As[kk0 + 2][r] = av.z; As[kk0 + 3][r] = av.w;
        }
        // stage B tile (16 k x 64 cols)
        {
            const int kk = tid >> 4, c0 = (tid & 15) << 2;
            *reinterpret_cast<float4*>(&Bs[kk][c0]) =
                *reinterpret_cast<const float4*>(&Bw[(size_t)(kt + kk) * Nc + nt + c0]);
        }
        __syncthreads();
        #pragma unroll
        for (int kk = 0; kk < 16; ++kk) {
            const float4 a4 = *reinterpret_cast<const float4*>(&As[kk][row0]);
            const float4 b4 = *reinterpret_cast<const float4*>(&Bs[kk][col0]);
            const float av[4] = {a4.x, a4.y, a4.z, a4.w};
            const float bv[4] = {b4.x, b4.y, b4.z, b4.w};
            #pragma unroll
            for (int i = 0; i < 4; ++i)
                #pragma unroll
                for (int j = 0; j < 4; ++j)
                    acc[i][j] = fmaf(av[i], bv[j], acc[i][j]);
        }
        __syncthreads();
    }

    #pragma unroll
    for (int i = 0; i < 4; ++i) {
        const size_t row = (size_t)(mt + row0 + i);
        float o[4];
        #pragma unroll
        for (int j = 0; j < 4; ++j) {
            float v = acc[i][j];
            const int col = nt + col0 + j;
            if (bias)  v += bias[col];
            if (do_relu) v = fmaxf(v, 0.0f);
            if (resid) v += resid[row * Nc + col];
            o[j] = v;
        }
        *reinterpret_cast<float4*>(&C[row * Nc + nt + col0]) =
            make_float4(o[0], o[1], o[2], o[3]);
    }
}

// ---------------------------------------------------------------------------
// Flash attention (conventional branch). One block per (q-tile 64, head, batch).
// Q/K staged transposed ([d][row]) so S-compute does conflict-free float4 LDS
// reads; P tile rotation-swizzled (col' = (col+row)&63) for conflict-free PV.
// Online softmax entirely in registers (16-lane shfl_xor row reductions).
// Writes att_c into att[:, 0:512] at column h*64+d.
// ---------------------------------------------------------------------------
__global__ __launch_bounds__(256) void flash_kernel(
    const float* __restrict__ Q, const float* __restrict__ K,
    const float* __restrict__ V, float* __restrict__ att)
{
    __shared__ float QsT[64][64];   // [d][qrow]
    __shared__ float KsT[64][64];   // [d][krow]
    __shared__ float Vs[64][64];    // [krow][d]
    __shared__ float Ss[64][64];    // P, rotation-swizzled

    const int tid = threadIdx.x;
    const int tx = tid & 15, ty = tid >> 4;
    const int row0 = ty * 4, col0 = tx * 4;
    const int qt = blockIdx.x, h = blockIdx.y, b = blockIdx.z;
    const size_t hbase = (size_t)b * N_ * DK_ + (size_t)h * HK_;

    // stage Q tile (transposed)
    #pragma unroll
    for (int it = 0; it < 4; ++it) {
        const int f = tid + it * 256;
        const int rr = f >> 4, d0 = (f & 15) << 2;
        const float4 qv = *reinterpret_cast<const float4*>(
            &Q[hbase + (size_t)(qt * 64 + rr) * DK_ + d0]);
        QsT[d0 + 0][rr] = qv.x; QsT[d0 + 1][rr] = qv.y;
        QsT[d0 + 2][rr] = qv.z; QsT[d0 + 3][rr] = qv.w;
    }

    float m_reg[4], l_reg[4], o[4][4];
    #pragma unroll
    for (int i = 0; i < 4; ++i) {
        m_reg[i] = -1e30f; l_reg[i] = 0.0f;
        #pragma unroll
        for (int j = 0; j < 4; ++j) o[i][j] = 0.0f;
    }

    for (int kt = 0; kt < N_ / 64; ++kt) {
        __syncthreads();   // previous PV done (and Q stage visible on iter 0)
        // stage K (transposed) and V (straight)
        #pragma unroll
        for (int it = 0; it < 4; ++it) {
            const int f = tid + it * 256;
            const int rr = f >> 4, d0 = (f & 15) << 2;
            const float4 kv = *reinterpret_cast<const float4*>(
                &K[hbase + (size_t)(kt * 64 + rr) * DK_ + d0]);
            KsT[d0 + 0][rr] = kv.x; KsT[d0 + 1][rr] = kv.y;
            KsT[d0 + 2][rr] = kv.z; KsT[d0 + 3][rr] = kv.w;
            *reinterpret_cast<float4*>(&Vs[rr][d0]) =
                *reinterpret_cast<const float4*>(
                    &V[hbase + (size_t)(kt * 64 + rr) * DK_ + d0]);
        }
        __syncthreads();

        // S = Q K^T
        float s[4][4] = {};
        #pragma unroll 4
        for (int d = 0; d < 64; ++d) {
            const float4 a4 = *reinterpret_cast<const float4*>(&QsT[d][row0]);
            const float4 b4 = *reinterpret_cast<const float4*>(&KsT[d][col0]);
            const float av[4] = {a4.x, a4.y, a4.z, a4.w};
            const float bv[4] = {b4.x, b4.y, b4.z, b4.w};
            #pragma unroll
            for (int i = 0; i < 4; ++i)
                #pragma unroll
                for (int j = 0; j < 4; ++j)
                    s[i][j] = fmaf(av[i], bv[j], s[i][j]);
        }

        // online softmax, per row (row0+i), reduced across the 16 tx lanes
        float fac[4];
        #pragma unroll
        for (int i = 0; i < 4; ++i) {
            #pragma unroll
            for (int j = 0; j < 4; ++j) s[i][j] *= SCALE_;
            float tm = fmaxf(fmaxf(s[i][0], s[i][1]), fmaxf(s[i][2], s[i][3]));
            tm = fmaxf(tm, __shfl_xor(tm, 1));
            tm = fmaxf(tm, __shfl_xor(tm, 2));
            tm = fmaxf(tm, __shfl_xor(tm, 4));
            tm = fmaxf(tm, __shfl_xor(tm, 8));
            const float newm = fmaxf(m_reg[i], tm);
            fac[i] = __expf(m_reg[i] - newm);
            m_reg[i] = newm;
            float rs = 0.0f;
            #pragma unroll
            for (int j = 0; j < 4; ++j) {
                const float p = __expf(s[i][j] - newm);
                s[i][j] = p; rs += p;
            }
            rs += __shfl_xor(rs, 1);
            rs += __shfl_xor(rs, 2);
            rs += __shfl_xor(rs, 4);
            rs += __shfl_xor(rs, 8);
            l_reg[i] = l_reg[i] * fac[i] + rs;
        }
        // write P (rotation swizzle: col' = (col + row) & 63)
        #pragma unroll
        for (int i = 0; i < 4; ++i) {
            const int r = row0 + i;
            #pragma unroll
            for (int j = 0; j < 4; ++j)
                Ss[r][(col0 + j + r) & 63] = s[i][j];
        }
        __syncthreads();

        // O = O*fac + P @ V
        #pragma unroll
        for (int i = 0; i < 4; ++i)
            #pragma unroll
            for (int j = 0; j < 4; ++j) o[i][j] *= fac[i];
        #pragma unroll 2
        for (int d = 0; d < 64; ++d) {
            float pv[4];
            #pragma unroll
            for (int i = 0; i < 4; ++i)
                pv[i] = Ss[row0 + i][(d + row0 + i) & 63];
            const float4 v4 = *reinterpret_cast<const float4*>(&Vs[d][col0]);
            const float vv[4] = {v4.x, v4.y, v4.z, v4.w};
            #pragma unroll
            for (int i = 0; i < 4; ++i)
                #pragma unroll
                for (int j = 0; j < 4; ++j)
                    o[i][j] = fmaf(pv[i], vv[j], o[i][j]);
        }
    }

    #pragma unroll
    for (int i = 0; i < 4; ++i) {
        const float inv = 1.0f / l_reg[i];
        const size_t row = (size_t)b * N_ + qt * 64 + row0 + i;
        *reinterpret_cast<float4*>(&att[row * (2 * DK_) + h * HK_ + col0]) =
            make_float4(o[i][0] * inv, o[i][1] * inv, o[i][2] * inv, o[i][3] * inv);
    }
}

// ---------------------------------------------------------------------------
// Feature branch step 1: S_f[kd,qd] = sum_n K[n,kd]*Q[n,qd]; dist_f = softmax
// over qd. One block per (h,b); register softmax; float4 global write.
// ---------------------------------------------------------------------------
__global__ __launch_bounds__(256) void featS_kernel(
    const float* __restrict__ K, const float* __restrict__ Q,
    float* __restrict__ distf)
{
    __shared__ float Kt[64][64];   // [n][kd]
    __shared__ float Qt[64][64];   // [n][qd]
    const int tid = threadIdx.x;
    const int tx = tid & 15, ty = tid >> 4;
    const int row0 = ty * 4, col0 = tx * 4;
    const int h = blockIdx.x, b = blockIdx.y;
    const size_t hbase = (size_t)b * N_ * DK_ + (size_t)h * HK_;

    float acc[4][4] = {};
    for (int nt = 0; nt < N_ / 64; ++nt) {
        __syncthreads();
        #pragma unroll
        for (int it = 0; it < 4; ++it) {
            const int f = tid + it * 256;
            const int rr = f >> 4, d0 = (f & 15) << 2;
            *reinterpret_cast<float4*>(&Kt[rr][d0]) =
                *reinterpret_cast<const float4*>(
                    &K[hbase + (size_t)(nt * 64 + rr) * DK_ + d0]);
            *reinterpret_cast<float4*>(&Qt[rr][d0]) =
                *reinterpret_cast<const float4*>(
                    &Q[hbase + (size_t)(nt * 64 + rr) * DK_ + d0]);
        }
        __syncthreads();
        #pragma unroll 4
        for (int nn = 0; nn < 64; ++nn) {
            const float4 k4 = *reinterpret_cast<const float4*>(&Kt[nn][row0]);
            const float4 q4 = *reinterpret_cast<const float4*>(&Qt[nn][col0]);
            const float kv[4] = {k4.x, k4.y, k4.z, k4.w};
            const float qv[4] = {q4.x, q4.y, q4.z, q4.w};
            #pragma unroll
            for (int i = 0; i < 4; ++i)
                #pragma unroll
                for (int j = 0; j < 4; ++j)
                    acc[i][j] = fmaf(kv[i], qv[j], acc[i][j]);
        }
    }

    #pragma unroll
    for (int i = 0; i < 4; ++i) {
        float tm = -1e30f;
        #pragma unroll
        for (int j = 0; j < 4; ++j) {
            acc[i][j] *= SCALE_;
            tm = fmaxf(tm, acc[i][j]);
        }
        tm = fmaxf(tm, __shfl_xor(tm, 1));
        tm = fmaxf(tm, __shfl_xor(tm, 2));
        tm = fmaxf(tm, __shfl_xor(tm, 4));
        tm = fmaxf(tm, __shfl_xor(tm, 8));
        float rs = 0.0f;
        #pragma unroll
        for (int j = 0; j < 4; ++j) {
            acc[i][j] = __expf(acc[i][j] - tm);
            rs += acc[i][j];
        }
        rs += __shfl_xor(rs, 1);
        rs += __shfl_xor(rs, 2);
        rs += __shfl_xor(rs, 4);
        rs += __shfl_xor(rs, 8);
        const float inv = 1.0f / rs;
        const size_t base = ((size_t)(b * NH_ + h) * 64 + row0 + i) * 64 + col0;
        *reinterpret_cast<float4*>(&distf[base]) =
            make_float4(acc[i][0] * inv, acc[i][1] * inv,
                        acc[i][2] * inv, acc[i][3] * inv);
    }
}

// ---------------------------------------------------------------------------
// Feature branch step 2: att_f[n,q] = sum_d V[n,d] * dist_f[d,q].
// Grid (N/128, NH, B); writes att[:, 512:1024] at column 512 + h*64 + q.
// ---------------------------------------------------------------------------
__global__ __launch_bounds__(256) void featAV_kernel(
    const float* __restrict__ V, const float* __restrict__ distf,
    float* __restrict__ att)
{
    __shared__ float Ps[64][64];
    __shared__ float Vt[32][64];
    const int tid = threadIdx.x;
    const int nt = blockIdx.x, h = blockIdx.y, b = blockIdx.z;
    const size_t hbase = (size_t)b * N_ * DK_ + (size_t)h * HK_;

    #pragma unroll
    for (int it = 0; it < 4; ++it) {
        const int f = tid + it * 256;
        const int rr = f >> 4, d0 = (f & 15) << 2;
        *reinterpret_cast<float4*>(&Ps[rr][d0]) =
            *reinterpret_cast<const float4*>(
                &distf[((size_t)(b * NH_ + h) * 64 + rr) * 64 + d0]);
    }

    const int q = tid & 63, wi = tid >> 6;
    for (int sub = 0; sub < 4; ++sub) {
        __syncthreads();
        #pragma unroll
        for (int it = 0; it < 2; ++it) {
            const int f = tid + it * 256;
            const int rr = f >> 4, d0 = (f & 15) << 2;
            *reinterpret_cast<float4*>(&Vt[rr][d0]) =
                *reinterpret_cast<const float4*>(
                    &V[hbase + (size_t)(nt * 128 + sub * 32 + rr) * DK_ + d0]);
        }
        __syncthreads();
        #pragma unroll
        for (int rr8 = 0; rr8 < 8; ++rr8) {
            const int r = wi * 8 + rr8;
            float acc = 0.0f;
            #pragma unroll 8
            for (int d = 0; d < 64; ++d)
                acc = fmaf(Vt[r][d], Ps[d][q], acc);
            att[((size_t)b * N_ + nt * 128 + sub * 32 + r) * (2 * DK_)
                + 512 + h * HK_ + q] = acc;
        }
    }
}

// ---------------------------------------------------------------------------
// LayerNorm over rows of fc[8192,512]. One block (256 thr) per row.
// ---------------------------------------------------------------------------
__global__ __launch_bounds__(256) void ln_kernel(
    const float* __restrict__ fc, const float* __restrict__ gamma,
    const float* __restrict__ beta, float* __restrict__ out)
{
    __shared__ float red[8];
    const int row = blockIdx.x, tid = threadIdx.x;
    const int c = tid * 2;
    const float2 v = *reinterpret_cast<const float2*>(&fc[(size_t)row * D_ + c]);
    float s = v.x + v.y;
    float sq = v.x * v.x + v.y * v.y;
    #pragma unroll
    for (int off = 32; off >= 1; off >>= 1) {
        s  += __shfl_xor(s, off);
        sq += __shfl_xor(sq, off);
    }
    const int lane = tid & 63, w = tid >> 6;
    if (lane == 0) { red[w] = s; red[4 + w] = sq; }
    __syncthreads();
    s  = red[0] + red[1] + red[2] + red[3];
    sq = red[4] + red[5] + red[6] + red[7];
    const float mu = s * (1.0f / D_);
    const float var = sq * (1.0f / D_) - mu * mu;
    const float rstd = rsqrtf(var + LN_EPS_);
    float2 o;
    o.x = (v.x - mu) * rstd * gamma[c] + beta[c];
    o.y = (v.y - mu) * rstd * gamma[c + 1] + beta[c + 1];
    *reinterpret_cast<float2*>(&out[(size_t)row * D_ + c]) = o;
}

// ---------------------------------------------------------------------------
extern "C" void kernel_launch(void* const* d_in, const int* in_sizes, int n_in,
                              void* d_out, int out_size, void* d_ws, size_t ws_size,
                              hipStream_t stream)
{
    (void)in_sizes; (void)n_in; (void)out_size; (void)ws_size;
    const float* x     = (const float*)d_in[0];
    const float* Wq    = (const float*)d_in[1];
    const float* Wk    = (const float*)d_in[2];
    const float* Wv    = (const float*)d_in[3];
    const float* Wf    = (const float*)d_in[4];
    const float* bf    = (const float*)d_in[5];
    const float* gamma = (const float*)d_in[6];
    const float* beta  = (const float*)d_in[7];
    float* out = (float*)d_out;

    float* ws = (float*)d_ws;
    const size_t SZ = (size_t)B_ * N_ * DK_;            // 4,194,304
    float* q     = ws;
    float* kbuf  = q + SZ;
    float* vbuf  = kbuf + SZ;
    float* att   = vbuf + SZ;                            // B*N*1024
    float* distf = att + (size_t)B_ * N_ * 2 * DK_;      // 131,072
    float* fcout = q;                                    // reuse (q dead by then)

    const dim3 blk(256);
    const int M = B_ * N_;

    // projections: q/k/v = x @ W
    gemm_kernel<<<dim3(DK_ / 64, M / 64), blk, 0, stream>>>(
        x, Wq, q, M, DK_, D_, nullptr, nullptr, 0);
    gemm_kernel<<<dim3(DK_ / 64, M / 64), blk, 0, stream>>>(
        x, Wk, kbuf, M, DK_, D_, nullptr, nullptr, 0);
    gemm_kernel<<<dim3(DK_ / 64, M / 64), blk, 0, stream>>>(
        x, Wv, vbuf, M, DK_, D_, nullptr, nullptr, 0);

    // conventional branch -> att[:, 0:512]
    flash_kernel<<<dim3(N_ / 64, NH_, B_), blk, 0, stream>>>(q, kbuf, vbuf, att);

    // feature branch -> att[:, 512:1024]
    featS_kernel<<<dim3(NH_, B_), blk, 0, stream>>>(kbuf, q, distf);
    featAV_kernel<<<dim3(N_ / 128, NH_, B_), blk, 0, stream>>>(vbuf, distf, att);

    // FC + bias + relu + residual
    gemm_kernel<<<dim3(D_ / 64, M / 64), blk, 0, stream>>>(
        att, Wf, fcout, M, D_, 2 * DK_, bf, x, 1);

    // LayerNorm
    ln_kernel<<<dim3(M), blk, 0, stream>>>(fcout, gamma, beta, out);
}

// Round 2
// 354.878 us; speedup vs baseline: 3.3484x; 3.3484x over previous
//
#include <hip/hip_runtime.h>
#include <math.h>
#include <stdint.h>

#define B_   4
#define N_   2048
#define D_   512
#define DK_  512
#define NH_  8
#define HK_  64
#define SCALE_ 0.125f
#define LN_EPS_ 1e-5f

typedef unsigned short u16;
typedef __attribute__((ext_vector_type(8))) short short8;
typedef __attribute__((ext_vector_type(4))) float f32x4;
typedef __attribute__((ext_vector_type(8))) unsigned short u16x8;

__device__ __forceinline__ u16 f2bf(float x) {
    uint32_t u = __builtin_bit_cast(uint32_t, x);
    return (u16)((u + 0x7fffu + ((u >> 16) & 1u)) >> 16);
}
__device__ __forceinline__ float b2f(u16 v) {
    return __builtin_bit_cast(float, (uint32_t)v << 16);
}

// async global->LDS, 16B per lane. Dest must be the wave-uniform base; HW
// writes lane i at base + i*16. Global src is per-lane.
__device__ __forceinline__ void gload16(const void* g, void* l) {
    __builtin_amdgcn_global_load_lds(
        reinterpret_cast<const __attribute__((address_space(1))) void*>(
            reinterpret_cast<uintptr_t>(g)),
        reinterpret_cast<__attribute__((address_space(3))) void*>(
            static_cast<uint32_t>(reinterpret_cast<uintptr_t>(l))),
        16, 0, 0);
}

// ---------------------------------------------------------------------------
// fp32 -> bf16 elementwise convert (8 elems/thread)
// ---------------------------------------------------------------------------
__global__ __launch_bounds__(256) void conv_bf16_kernel(
    const float* __restrict__ src, u16* __restrict__ dst, int n)
{
    const int i = (blockIdx.x * 256 + threadIdx.x) * 8;
    if (i >= n) return;
    const float4 a = *reinterpret_cast<const float4*>(&src[i]);
    const float4 b = *reinterpret_cast<const float4*>(&src[i + 4]);
    u16x8 o;
    o[0] = f2bf(a.x); o[1] = f2bf(a.y); o[2] = f2bf(a.z); o[3] = f2bf(a.w);
    o[4] = f2bf(b.x); o[5] = f2bf(b.y); o[6] = f2bf(b.z); o[7] = f2bf(b.w);
    *reinterpret_cast<u16x8*>(&dst[i]) = o;
}

// ---------------------------------------------------------------------------
// Transpose-convert: W[K][Nc] fp32 -> Wt[Nc][K] bf16 (32x32 LDS tiles)
// ---------------------------------------------------------------------------
__global__ __launch_bounds__(256) void tc_kernel(
    const float* __restrict__ W, u16* __restrict__ Wt, int K, int Nc)
{
    __shared__ float t[32][33];
    const int tid = threadIdx.x;
    const int kt = blockIdx.y * 32, nt = blockIdx.x * 32;
    {
        const int r = tid >> 3, c0 = (tid & 7) * 4;
        const float4 v = *reinterpret_cast<const float4*>(
            &W[(size_t)(kt + r) * Nc + nt + c0]);
        t[r][c0] = v.x; t[r][c0 + 1] = v.y; t[r][c0 + 2] = v.z; t[r][c0 + 3] = v.w;
    }
    __syncthreads();
    {
        const int nidx = tid >> 3, kc = (tid & 7) * 4;
        u16 o[4];
        #pragma unroll
        for (int j = 0; j < 4; ++j) o[j] = f2bf(t[kc + j][nidx]);
        *reinterpret_cast<ushort4*>(&Wt[(size_t)(nt + nidx) * K + kt + kc]) =
            make_ushort4(o[0], o[1], o[2], o[3]);
    }
}

// ---------------------------------------------------------------------------
// Per-head V transpose: v[b][n][h*64+d] bf16 -> vt[(b*8+h)*64+d][n] bf16
// ---------------------------------------------------------------------------
__global__ __launch_bounds__(256) void vtrans_kernel(
    const u16* __restrict__ v, u16* __restrict__ vt)
{
    __shared__ u16 t[64][72];
    const int tid = threadIdx.x;
    const int nt = blockIdx.x * 64, h = blockIdx.y, b = blockIdx.z;
    #pragma unroll
    for (int i = 0; i < 2; ++i) {
        const int idx = tid + i * 256;
        const int r = idx >> 3, c0 = (idx & 7) * 8;
        *reinterpret_cast<u16x8*>(&t[r][c0]) =
            *reinterpret_cast<const u16x8*>(
                &v[((size_t)(b * N_ + nt + r)) * DK_ + h * HK_ + c0]);
    }
    __syncthreads();
    #pragma unroll
    for (int i = 0; i < 2; ++i) {
        const int idx = tid + i * 256;
        const int d = idx >> 3, k0 = (idx & 7) * 8;
        u16x8 o;
        #pragma unroll
        for (int j = 0; j < 8; ++j) o[j] = t[k0 + j][d];
        *reinterpret_cast<u16x8*>(
            &vt[(((size_t)(b * NH_ + h)) * HK_ + d) * N_ + nt + k0]) = o;
    }
}

// ---------------------------------------------------------------------------
// bf16 MFMA GEMM: C[M][Nc] = epi(A[M][K] @ Bt[Nc][K]^T). 128x128 tile, BK=64,
// 4 waves (2x2), each wave 64x64 via 4x4 16x16x32 frags. global_load_lds with
// pre-swizzled source; LDS rows XOR-swizzled (byte ^= (row&7)<<4).
// ---------------------------------------------------------------------------
__global__ __launch_bounds__(256) void gemm_bf16_kernel(
    const u16* __restrict__ A, const u16* __restrict__ Bt,
    float* __restrict__ Cf, u16* __restrict__ Cb,
    int M, int Nc, int K,
    const float* __restrict__ bias, const float* __restrict__ resid, int relu)
{
    __shared__ u16 As[128 * 64];
    __shared__ u16 Bs[128 * 64];
    const int tid = threadIdx.x;
    const int lane = tid & 63, wave = tid >> 6;
    const int wm = wave >> 1, wn = wave & 1;
    const int mt = blockIdx.y * 128, nt = blockIdx.x * 128;
    const int l15 = lane & 15, lg = lane >> 4;

    f32x4 acc[4][4] = {};

    for (int kt = 0; kt < K; kt += 64) {
        __syncthreads();
        #pragma unroll
        for (int i = 0; i < 4; ++i) {
            const int ob = (wave * 4 + i) * 1024;
            const int o = ob + lane * 16;
            const int row = o >> 7;
            const int inner = (o & 127) ^ ((row & 7) << 4);
            gload16((const char*)A + ((size_t)(mt + row) * K + kt) * 2 + inner,
                    (char*)As + ob);
            gload16((const char*)Bt + ((size_t)(nt + row) * K + kt) * 2 + inner,
                    (char*)Bs + ob);
        }
        __syncthreads();
        #pragma unroll
        for (int ks = 0; ks < 2; ++ks) {
            const int kb = ks * 32 + lg * 8;
            short8 af[4], bfr[4];
            #pragma unroll
            for (int mi = 0; mi < 4; ++mi) {
                const int r = wm * 64 + mi * 16 + l15;
                af[mi] = *reinterpret_cast<const short8*>(
                    &As[r * 64 + (kb ^ ((r & 7) << 3))]);
            }
            #pragma unroll
            for (int ni = 0; ni < 4; ++ni) {
                const int r = wn * 64 + ni * 16 + l15;
                bfr[ni] = *reinterpret_cast<const short8*>(
                    &Bs[r * 64 + (kb ^ ((r & 7) << 3))]);
            }
            #pragma unroll
            for (int mi = 0; mi < 4; ++mi)
                #pragma unroll
                for (int ni = 0; ni < 4; ++ni)
                    acc[mi][ni] = __builtin_amdgcn_mfma_f32_16x16x32_bf16(
                        af[mi], bfr[ni], acc[mi][ni], 0, 0, 0);
        }
    }

    #pragma unroll
    for (int mi = 0; mi < 4; ++mi) {
        #pragma unroll
        for (int ni = 0; ni < 4; ++ni) {
            #pragma unroll
            for (int jj = 0; jj < 4; ++jj) {
                const size_t row = (size_t)(mt + wm * 64 + mi * 16 + lg * 4 + jj);
                const int col = nt + wn * 64 + ni * 16 + l15;
                float v = acc[mi][ni][jj];
                if (bias) v += bias[col];
                if (relu) v = fmaxf(v, 0.0f);
                if (resid) v += resid[row * Nc + col];
                if (Cb) Cb[row * Nc + col] = f2bf(v);
                else    Cf[row * Nc + col] = v;
            }
        }
    }
}

// ---------------------------------------------------------------------------
// Flash attention, bf16 MFMA. Block = 64 q-rows x (h,b); 4 waves x 16 q-rows.
// Q frags in registers; K and pre-transposed V staged via swizzled-source
// global_load_lds; online softmax on C-frags; P->bf16->swizzled LDS->A-frags.
// ---------------------------------------------------------------------------
__global__ __launch_bounds__(256) void flash_bf16_kernel(
    const u16* __restrict__ Qb, const u16* __restrict__ Kb,
    const u16* __restrict__ Vt, u16* __restrict__ att)
{
    __shared__ u16 Ks[64 * 64];
    __shared__ u16 Vs[64 * 64];   // [d][key]
    __shared__ u16 Ps[64 * 64];   // [q][key]
    const int tid = threadIdx.x;
    const int lane = tid & 63, wave = tid >> 6;
    const int l15 = lane & 15, lg = lane >> 4;
    const int qt = blockIdx.x, h = blockIdx.y, b = blockIdx.z;

    short8 aq[2];
    {
        const int qrow = qt * 64 + wave * 16 + l15;
        const u16* qp = Qb + ((size_t)(b * N_ + qrow)) * DK_ + h * HK_ + lg * 8;
        aq[0] = *reinterpret_cast<const short8*>(qp);
        aq[1] = *reinterpret_cast<const short8*>(qp + 32);
    }

    f32x4 o[4] = {};
    float m_[4], l_[4];
    #pragma unroll
    for (int j = 0; j < 4; ++j) { m_[j] = -1e30f; l_[j] = 0.0f; }

    for (int kt = 0; kt < N_ / 64; ++kt) {
        __syncthreads();
        #pragma unroll
        for (int i = 0; i < 2; ++i) {
            const int ob = (wave * 2 + i) * 1024;
            const int o_ = ob + lane * 16;
            const int row = o_ >> 7;
            const int inner = (o_ & 127) ^ ((row & 7) << 4);
            gload16((const char*)Kb +
                        ((size_t)(b * N_ + kt * 64 + row) * DK_ + h * HK_) * 2 + inner,
                    (char*)Ks + ob);
            gload16((const char*)Vt +
                        (((size_t)(b * NH_ + h) * HK_ + row) * N_ + kt * 64) * 2 + inner,
                    (char*)Vs + ob);
        }
        __syncthreads();

        // S = Q K^T  (per wave: 16q x 64key)
        f32x4 s[4] = {};
        #pragma unroll
        for (int ks = 0; ks < 2; ++ks) {
            const int kb2 = ks * 32 + lg * 8;
            #pragma unroll
            for (int t = 0; t < 4; ++t) {
                const int r = t * 16 + l15;
                const short8 bk = *reinterpret_cast<const short8*>(
                    &Ks[r * 64 + (kb2 ^ ((r & 7) << 3))]);
                s[t] = __builtin_amdgcn_mfma_f32_16x16x32_bf16(aq[ks], bk, s[t], 0, 0, 0);
            }
        }

        // online softmax per row (row = lg*4+jj), reduce across 16 l15 lanes
        float fac[4];
        #pragma unroll
        for (int jj = 0; jj < 4; ++jj) {
            float v0 = s[0][jj] * SCALE_, v1 = s[1][jj] * SCALE_;
            float v2 = s[2][jj] * SCALE_, v3 = s[3][jj] * SCALE_;
            float rm = fmaxf(fmaxf(v0, v1), fmaxf(v2, v3));
            rm = fmaxf(rm, __shfl_xor(rm, 1));
            rm = fmaxf(rm, __shfl_xor(rm, 2));
            rm = fmaxf(rm, __shfl_xor(rm, 4));
            rm = fmaxf(rm, __shfl_xor(rm, 8));
            const float newm = fmaxf(m_[jj], rm);
            fac[jj] = __expf(m_[jj] - newm);
            m_[jj] = newm;
            v0 = __expf(v0 - newm); v1 = __expf(v1 - newm);
            v2 = __expf(v2 - newm); v3 = __expf(v3 - newm);
            float rs = v0 + v1 + v2 + v3;
            rs += __shfl_xor(rs, 1);
            rs += __shfl_xor(rs, 2);
            rs += __shfl_xor(rs, 4);
            rs += __shfl_xor(rs, 8);
            l_[jj] = l_[jj] * fac[jj] + rs;
            const int prow = wave * 16 + lg * 4 + jj;
            const int pb = prow * 64, sw = (prow & 7) << 3;
            Ps[pb + ((l15     ) ^ sw)] = f2bf(v0);
            Ps[pb + ((l15 + 16) ^ sw)] = f2bf(v1);
            Ps[pb + ((l15 + 32) ^ sw)] = f2bf(v2);
            Ps[pb + ((l15 + 48) ^ sw)] = f2bf(v3);
        }

        // O = O*fac + P V   (wave reads only its own 16 P rows -> no barrier)
        #pragma unroll
        for (int t = 0; t < 4; ++t)
            #pragma unroll
            for (int jj = 0; jj < 4; ++jj)
                o[t][jj] *= fac[jj];
        #pragma unroll
        for (int ks = 0; ks < 2; ++ks) {
            const int kb2 = ks * 32 + lg * 8;
            const int pr = wave * 16 + l15;
            const short8 ap = *reinterpret_cast<const short8*>(
                &Ps[pr * 64 + (kb2 ^ ((pr & 7) << 3))]);
            #pragma unroll
            for (int t = 0; t < 4; ++t) {
                const int dr = t * 16 + l15;
                const short8 bv = *reinterpret_cast<const short8*>(
                    &Vs[dr * 64 + (kb2 ^ ((dr & 7) << 3))]);
                o[t] = __builtin_amdgcn_mfma_f32_16x16x32_bf16(ap, bv, o[t], 0, 0, 0);
            }
        }
    }

    #pragma unroll
    for (int jj = 0; jj < 4; ++jj) {
        const float inv = 1.0f / l_[jj];
        const size_t row = (size_t)b * N_ + qt * 64 + wave * 16 + lg * 4 + jj;
        #pragma unroll
        for (int t = 0; t < 4; ++t)
            att[row * (2 * DK_) + h * HK_ + t * 16 + l15] = f2bf(o[t][jj] * inv);
    }
}

// ---------------------------------------------------------------------------
// Feature branch step 1 (fp32 math, bf16 inputs): dist_f = softmax_q(K^T Q / 8)
// ---------------------------------------------------------------------------
__global__ __launch_bounds__(256) void featS_kernel(
    const u16* __restrict__ K, const u16* __restrict__ Q,
    float* __restrict__ distf)
{
    __shared__ float Kt[64][68];
    __shared__ float Qt[64][68];
    const int tid = threadIdx.x;
    const int tx = tid & 15, ty = tid >> 4;
    const int row0 = ty * 4, col0 = tx * 4;
    const int h = blockIdx.x, b = blockIdx.y;
    const size_t hbase = (size_t)b * N_ * DK_ + (size_t)h * HK_;

    float acc[4][4] = {};
    for (int nt = 0; nt < N_ / 64; ++nt) {
        __syncthreads();
        #pragma unroll
        for (int it = 0; it < 2; ++it) {
            const int idx = tid + it * 256;
            const int rr = idx >> 3, d0 = (idx & 7) * 8;
            const u16x8 kv = *reinterpret_cast<const u16x8*>(
                &K[hbase + (size_t)(nt * 64 + rr) * DK_ + d0]);
            const u16x8 qv = *reinterpret_cast<const u16x8*>(
                &Q[hbase + (size_t)(nt * 64 + rr) * DK_ + d0]);
            #pragma unroll
            for (int j = 0; j < 8; ++j) {
                Kt[rr][d0 + j] = b2f(kv[j]);
                Qt[rr][d0 + j] = b2f(qv[j]);
            }
        }
        __syncthreads();
        #pragma unroll 4
        for (int nn = 0; nn < 64; ++nn) {
            const float4 k4 = *reinterpret_cast<const float4*>(&Kt[nn][row0]);
            const float4 q4 = *reinterpret_cast<const float4*>(&Qt[nn][col0]);
            const float kv[4] = {k4.x, k4.y, k4.z, k4.w};
            const float qv[4] = {q4.x, q4.y, q4.z, q4.w};
            #pragma unroll
            for (int i = 0; i < 4; ++i)
                #pragma unroll
                for (int j = 0; j < 4; ++j)
                    acc[i][j] = fmaf(kv[i], qv[j], acc[i][j]);
        }
    }

    #pragma unroll
    for (int i = 0; i < 4; ++i) {
        float tm = -1e30f;
        #pragma unroll
        for (int j = 0; j < 4; ++j) {
            acc[i][j] *= SCALE_;
            tm = fmaxf(tm, acc[i][j]);
        }
        tm = fmaxf(tm, __shfl_xor(tm, 1));
        tm = fmaxf(tm, __shfl_xor(tm, 2));
        tm = fmaxf(tm, __shfl_xor(tm, 4));
        tm = fmaxf(tm, __shfl_xor(tm, 8));
        float rs = 0.0f;
        #pragma unroll
        for (int j = 0; j < 4; ++j) {
            acc[i][j] = __expf(acc[i][j] - tm);
            rs += acc[i][j];
        }
        rs += __shfl_xor(rs, 1);
        rs += __shfl_xor(rs, 2);
        rs += __shfl_xor(rs, 4);
        rs += __shfl_xor(rs, 8);
        const float inv = 1.0f / rs;
        const size_t base = ((size_t)(b * NH_ + h) * 64 + row0 + i) * 64 + col0;
        *reinterpret_cast<float4*>(&distf[base]) =
            make_float4(acc[i][0] * inv, acc[i][1] * inv,
                        acc[i][2] * inv, acc[i][3] * inv);
    }
}

// ---------------------------------------------------------------------------
// Feature branch step 2: att_f[n,q] = sum_d V[n,d] * dist_f[d,q] -> bf16 att
// ---------------------------------------------------------------------------
__global__ __launch_bounds__(256) void featAV_kernel(
    const u16* __restrict__ V, const float* __restrict__ distf,
    u16* __restrict__ att)
{
    __shared__ float Ps[64][68];
    __shared__ float Vtl[32][68];
    const int tid = threadIdx.x;
    const int nt = blockIdx.x, h = blockIdx.y, b = blockIdx.z;
    const size_t hbase = (size_t)b * N_ * DK_ + (size_t)h * HK_;

    #pragma unroll
    for (int it = 0; it < 4; ++it) {
        const int f = tid + it * 256;
        const int rr = f >> 4, d0 = (f & 15) << 2;
        const float4 v = *reinterpret_cast<const float4*>(
            &distf[((size_t)(b * NH_ + h) * 64 + rr) * 64 + d0]);
        Ps[rr][d0] = v.x; Ps[rr][d0 + 1] = v.y; Ps[rr][d0 + 2] = v.z; Ps[rr][d0 + 3] = v.w;
    }

    const int q = tid & 63, wi = tid >> 6;
    for (int sub = 0; sub < 4; ++sub) {
        __syncthreads();
        {
            const int rr = tid >> 3, d0 = (tid & 7) * 8;
            const u16x8 vv = *reinterpret_cast<const u16x8*>(
                &V[hbase + (size_t)(nt * 128 + sub * 32 + rr) * DK_ + d0]);
            #pragma unroll
            for (int j = 0; j < 8; ++j) Vtl[rr][d0 + j] = b2f(vv[j]);
        }
        __syncthreads();
        #pragma unroll
        for (int rr8 = 0; rr8 < 8; ++rr8) {
            const int r = wi * 8 + rr8;
            float acc = 0.0f;
            #pragma unroll 8
            for (int d = 0; d < 64; ++d)
                acc = fmaf(Vtl[r][d], Ps[d][q], acc);
            att[((size_t)b * N_ + nt * 128 + sub * 32 + r) * (2 * DK_)
                + 512 + h * HK_ + q] = f2bf(acc);
        }
    }
}

// ---------------------------------------------------------------------------
// LayerNorm over rows of fc[8192,512] fp32 -> out fp32
// ---------------------------------------------------------------------------
__global__ __launch_bounds__(256) void ln_kernel(
    const float* __restrict__ fc, const float* __restrict__ gamma,
    const float* __restrict__ beta, float* __restrict__ out)
{
    __shared__ float red[8];
    const int row = blockIdx.x, tid = threadIdx.x;
    const int c = tid * 2;
    const float2 v = *reinterpret_cast<const float2*>(&fc[(size_t)row * D_ + c]);
    float s = v.x + v.y;
    float sq = v.x * v.x + v.y * v.y;
    #pragma unroll
    for (int off = 32; off >= 1; off >>= 1) {
        s  += __shfl_xor(s, off);
        sq += __shfl_xor(sq, off);
    }
    const int lane = tid & 63, w = tid >> 6;
    if (lane == 0) { red[w] = s; red[4 + w] = sq; }
    __syncthreads();
    s  = red[0] + red[1] + red[2] + red[3];
    sq = red[4] + red[5] + red[6] + red[7];
    const float mu = s * (1.0f / D_);
    const float var = sq * (1.0f / D_) - mu * mu;
    const float rstd = rsqrtf(var + LN_EPS_);
    float2 o;
    o.x = (v.x - mu) * rstd * gamma[c] + beta[c];
    o.y = (v.y - mu) * rstd * gamma[c + 1] + beta[c + 1];
    *reinterpret_cast<float2*>(&out[(size_t)row * D_ + c]) = o;
}

// ---------------------------------------------------------------------------
extern "C" void kernel_launch(void* const* d_in, const int* in_sizes, int n_in,
                              void* d_out, int out_size, void* d_ws, size_t ws_size,
                              hipStream_t stream)
{
    (void)in_sizes; (void)n_in; (void)out_size; (void)ws_size;
    const float* x     = (const float*)d_in[0];
    const float* Wq    = (const float*)d_in[1];
    const float* Wk    = (const float*)d_in[2];
    const float* Wv    = (const float*)d_in[3];
    const float* Wf    = (const float*)d_in[4];
    const float* bf    = (const float*)d_in[5];
    const float* gamma = (const float*)d_in[6];
    const float* beta  = (const float*)d_in[7];
    float* out = (float*)d_out;

    char* w = (char*)d_ws;
    const size_t SZE = (size_t)B_ * N_ * DK_;      // 4,194,304 elements
    u16* xb   = (u16*)w;                 w += SZE * 2;            // 8 MB
    u16* wqT  = (u16*)w;                 w += 512 * 512 * 2;
    u16* wkT  = (u16*)w;                 w += 512 * 512 * 2;
    u16* wvT  = (u16*)w;                 w += 512 * 512 * 2;
    u16* wfT  = (u16*)w;                 w += 512 * 1024 * 2;
    u16* qb   = (u16*)w;                 w += SZE * 2;
    u16* kb   = (u16*)w;                 w += SZE * 2;
    u16* vb   = (u16*)w;                 w += SZE * 2;
    u16* vt   = (u16*)w;                 w += SZE * 2;
    u16* attb = (u16*)w;                 w += SZE * 2 * 2;        // 16.8 MB
    float* distf = (float*)w;            w += (size_t)B_ * NH_ * 64 * 64 * 4;
    float* fcout = (float*)w;            /* 8192*512*4 = 16.8 MB */

    const dim3 blk(256);
    const int M = B_ * N_;

    // bf16 converts
    conv_bf16_kernel<<<dim3((B_ * N_ * D_) / 2048), blk, 0, stream>>>(x, xb, B_ * N_ * D_);
    tc_kernel<<<dim3(16, 16), blk, 0, stream>>>(Wq, wqT, 512, 512);
    tc_kernel<<<dim3(16, 16), blk, 0, stream>>>(Wk, wkT, 512, 512);
    tc_kernel<<<dim3(16, 16), blk, 0, stream>>>(Wv, wvT, 512, 512);
    tc_kernel<<<dim3(16, 32), blk, 0, stream>>>(Wf, wfT, 1024, 512);

    // projections (bf16 out)
    gemm_bf16_kernel<<<dim3(4, 64), blk, 0, stream>>>(
        xb, wqT, nullptr, qb, M, DK_, D_, nullptr, nullptr, 0);
    gemm_bf16_kernel<<<dim3(4, 64), blk, 0, stream>>>(
        xb, wkT, nullptr, kb, M, DK_, D_, nullptr, nullptr, 0);
    gemm_bf16_kernel<<<dim3(4, 64), blk, 0, stream>>>(
        xb, wvT, nullptr, vb, M, DK_, D_, nullptr, nullptr, 0);

    // per-head V transpose for the PV B-operand
    vtrans_kernel<<<dim3(N_ / 64, NH_, B_), blk, 0, stream>>>(vb, vt);

    // conventional branch -> att[:, 0:512]
    flash_bf16_kernel<<<dim3(N_ / 64, NH_, B_), blk, 0, stream>>>(qb, kb, vt, attb);

    // feature branch -> att[:, 512:1024]
    featS_kernel<<<dim3(NH_, B_), blk, 0, stream>>>(kb, qb, distf);
    featAV_kernel<<<dim3(N_ / 128, NH_, B_), blk, 0, stream>>>(vb, distf, attb);

    // FC + bias + relu + residual (fp32 out)
    gemm_bf16_kernel<<<dim3(4, 64), blk, 0, stream>>>(
        attb, wfT, fcout, nullptr, M, D_, 2 * DK_, bf, x, 1);

    // LayerNorm
    ln_kernel<<<dim3(M), blk, 0, stream>>>(fcout, gamma, beta, out);
}

// Round 3
// 162.717 us; speedup vs baseline: 7.3027x; 2.1809x over previous
//
#include <hip/hip_runtime.h>
#include <math.h>
#include <stdint.h>

#define B_   4
#define N_   2048
#define D_   512
#define DK_  512
#define NH_  8
#define HK_  64
#define LN_EPS_ 1e-5f
// softmax runs in exp2 domain: Q is pre-scaled by 1/sqrt(64) * log2(e)
#define QS_  0.18033688011112042f

typedef unsigned short u16;
typedef __attribute__((ext_vector_type(8))) short short8;
typedef __attribute__((ext_vector_type(4))) float f32x4;
typedef __attribute__((ext_vector_type(8))) unsigned short u16x8;

__device__ __forceinline__ u16 f2bf(float x) {          // RNE
    uint32_t u = __builtin_bit_cast(uint32_t, x);
    return (u16)((u + 0x7fffu + ((u >> 16) & 1u)) >> 16);
}
__device__ __forceinline__ u16 f2bf_fast(float x) {     // round-half-up (2 ops)
    return (u16)((__builtin_bit_cast(uint32_t, x) + 0x8000u) >> 16);
}
__device__ __forceinline__ float exp2f_fast(float x) {
    return __builtin_amdgcn_exp2f(x);
}

// async global->LDS, 16B/lane; LDS dest = wave-uniform base + lane*16
__device__ __forceinline__ void gload16(const void* g, void* l) {
    __builtin_amdgcn_global_load_lds(
        reinterpret_cast<const __attribute__((address_space(1))) void*>(
            reinterpret_cast<uintptr_t>(g)),
        reinterpret_cast<__attribute__((address_space(3))) void*>(
            static_cast<uint32_t>(reinterpret_cast<uintptr_t>(l))),
        16, 0, 0);
}

// ---------------------------------------------------------------------------
__global__ __launch_bounds__(256) void conv_bf16_kernel(
    const float* __restrict__ src, u16* __restrict__ dst, int n)
{
    const int i = (blockIdx.x * 256 + threadIdx.x) * 8;
    if (i >= n) return;
    const float4 a = *reinterpret_cast<const float4*>(&src[i]);
    const float4 b = *reinterpret_cast<const float4*>(&src[i + 4]);
    u16x8 o;
    o[0] = f2bf(a.x); o[1] = f2bf(a.y); o[2] = f2bf(a.z); o[3] = f2bf(a.w);
    o[4] = f2bf(b.x); o[5] = f2bf(b.y); o[6] = f2bf(b.z); o[7] = f2bf(b.w);
    *reinterpret_cast<u16x8*>(&dst[i]) = o;
}

// W[K][Nc] fp32 -> Wt[Nc][K] bf16
__global__ __launch_bounds__(256) void tc_kernel(
    const float* __restrict__ W, u16* __restrict__ Wt, int K, int Nc)
{
    __shared__ float t[32][33];
    const int tid = threadIdx.x;
    const int kt = blockIdx.y * 32, nt = blockIdx.x * 32;
    {
        const int r = tid >> 3, c0 = (tid & 7) * 4;
        const float4 v = *reinterpret_cast<const float4*>(
            &W[(size_t)(kt + r) * Nc + nt + c0]);
        t[r][c0] = v.x; t[r][c0 + 1] = v.y; t[r][c0 + 2] = v.z; t[r][c0 + 3] = v.w;
    }
    __syncthreads();
    {
        const int nidx = tid >> 3, kc = (tid & 7) * 4;
        u16 o[4];
        #pragma unroll
        for (int j = 0; j < 4; ++j) o[j] = f2bf(t[kc + j][nidx]);
        *reinterpret_cast<ushort4*>(&Wt[(size_t)(nt + nidx) * K + kt + kc]) =
            make_ushort4(o[0], o[1], o[2], o[3]);
    }
}

// v[b][n][h*64+d] -> vt[(b*8+h)*64+d][n]
__global__ __launch_bounds__(256) void vtrans_kernel(
    const u16* __restrict__ v, u16* __restrict__ vt)
{
    __shared__ u16 t[64][72];
    const int tid = threadIdx.x;
    const int nt = blockIdx.x * 64, h = blockIdx.y, b = blockIdx.z;
    #pragma unroll
    for (int i = 0; i < 2; ++i) {
        const int idx = tid + i * 256;
        const int r = idx >> 3, c0 = (idx & 7) * 8;
        *reinterpret_cast<u16x8*>(&t[r][c0]) =
            *reinterpret_cast<const u16x8*>(
                &v[((size_t)(b * N_ + nt + r)) * DK_ + h * HK_ + c0]);
    }
    __syncthreads();
    #pragma unroll
    for (int i = 0; i < 2; ++i) {
        const int idx = tid + i * 256;
        const int d = idx >> 3, k0 = (idx & 7) * 8;
        u16x8 o;
        #pragma unroll
        for (int j = 0; j < 8; ++j) o[j] = t[k0 + j][d];
        *reinterpret_cast<u16x8*>(
            &vt[(((size_t)(b * NH_ + h)) * HK_ + d) * N_ + nt + k0]) = o;
    }
}

// ---------------------------------------------------------------------------
// bf16 MFMA GEMM, tile BM x BN, BK=64, 4 waves (2x2). XCD-swizzled 1-D grid.
// MODE 1: QKV split epilogue (col<512 -> qb scaled by QS_, <1024 -> kb, else vb)
// MODE 2: fp32 out + bias + relu + resid
// ---------------------------------------------------------------------------
template<int BM, int BN, int MODE>
__global__ __launch_bounds__(256) void gemm_bf16(
    const u16* __restrict__ A, const u16* __restrict__ Bt,
    float* __restrict__ Cf, u16* __restrict__ qb, u16* __restrict__ kb,
    u16* __restrict__ vb, int M, int Nc, int K,
    const float* __restrict__ bias, const float* __restrict__ resid)
{
    constexpr int MI = BM / 32, NI = BN / 32;
    constexpr int AL = BM / 32, BL = BN / 32;   // 1KB staging chunks per wave
    __shared__ u16 As[BM * 64];
    __shared__ u16 Bs[BN * 64];
    const int tid = threadIdx.x;
    const int lane = tid & 63, wave = tid >> 6;
    const int wm = wave >> 1, wn = wave & 1;
    const int l15 = lane & 15, lg = lane >> 4;

    const int nwg = gridDim.x;
    const int bid = ((int)blockIdx.x & 7) * (nwg >> 3) + ((int)blockIdx.x >> 3);
    const int ntiles = Nc / BN;
    const int nt = (bid % ntiles) * BN;
    const int mt = (bid / ntiles) * BM;

    f32x4 acc[MI][NI] = {};

    for (int kt = 0; kt < K; kt += 64) {
        __syncthreads();
        #pragma unroll
        for (int i = 0; i < AL; ++i) {
            const int ob = (wave * AL + i) * 1024;
            const int o = ob + lane * 16;
            const int row = o >> 7;
            const int inner = (o & 127) ^ ((row & 7) << 4);
            gload16((const char*)A + ((size_t)(mt + row) * K + kt) * 2 + inner,
                    (char*)As + ob);
        }
        #pragma unroll
        for (int i = 0; i < BL; ++i) {
            const int ob = (wave * BL + i) * 1024;
            const int o = ob + lane * 16;
            const int row = o >> 7;
            const int inner = (o & 127) ^ ((row & 7) << 4);
            gload16((const char*)Bt + ((size_t)(nt + row) * K + kt) * 2 + inner,
                    (char*)Bs + ob);
        }
        __syncthreads();
        #pragma unroll
        for (int ks = 0; ks < 2; ++ks) {
            const int kb2 = ks * 32 + lg * 8;
            short8 af[MI], bfr[NI];
            #pragma unroll
            for (int mi = 0; mi < MI; ++mi) {
                const int r = wm * (BM / 2) + mi * 16 + l15;
                af[mi] = *reinterpret_cast<const short8*>(
                    &As[r * 64 + (kb2 ^ ((r & 7) << 3))]);
            }
            #pragma unroll
            for (int ni = 0; ni < NI; ++ni) {
                const int r = wn * (BN / 2) + ni * 16 + l15;
                bfr[ni] = *reinterpret_cast<const short8*>(
                    &Bs[r * 64 + (kb2 ^ ((r & 7) << 3))]);
            }
            #pragma unroll
            for (int mi = 0; mi < MI; ++mi)
                #pragma unroll
                for (int ni = 0; ni < NI; ++ni)
                    acc[mi][ni] = __builtin_amdgcn_mfma_f32_16x16x32_bf16(
                        af[mi], bfr[ni], acc[mi][ni], 0, 0, 0);
        }
    }

    #pragma unroll
    for (int mi = 0; mi < MI; ++mi) {
        #pragma unroll
        for (int ni = 0; ni < NI; ++ni) {
            #pragma unroll
            for (int jj = 0; jj < 4; ++jj) {
                const size_t row = (size_t)(mt + wm * (BM / 2) + mi * 16 + lg * 4 + jj);
                const int col = nt + wn * (BN / 2) + ni * 16 + l15;
                float v = acc[mi][ni][jj];
                if (MODE == 1) {
                    if (col < 512)       qb[row * 512 + col]        = f2bf(v * QS_);
                    else if (col < 1024) kb[row * 512 + col - 512]  = f2bf(v);
                    else                 vb[row * 512 + col - 1024] = f2bf(v);
                } else {
                    v += bias[col];
                    v = fmaxf(v, 0.0f);
                    v += resid[row * Nc + col];
                    Cf[row * Nc + col] = v;
                }
            }
        }
    }
}

// ---------------------------------------------------------------------------
// Flash attention, bf16 MFMA, exp2-domain softmax with deferred max + lazy l.
// 1-D grid 1024, XCD-swizzled so one (b,h)'s 32 q-blocks share an XCD L2.
// ---------------------------------------------------------------------------
__global__ __launch_bounds__(256) void flash_bf16_kernel(
    const u16* __restrict__ Qb, const u16* __restrict__ Kb,
    const u16* __restrict__ Vt, u16* __restrict__ att)
{
    __shared__ u16 Ks[64 * 64];
    __shared__ u16 Vs[64 * 64];   // [d][key]
    __shared__ u16 Ps[64 * 64];   // [q][key], XOR-swizzled
    const int tid = threadIdx.x;
    const int lane = tid & 63, wave = tid >> 6;
    const int l15 = lane & 15, lg = lane >> 4;
    const int lbid = (((int)blockIdx.x & 7) << 7) + ((int)blockIdx.x >> 3);
    const int qt = lbid & 31, h = (lbid >> 5) & 7, b = lbid >> 8;

    short8 aq[2];
    {
        const int qrow = qt * 64 + wave * 16 + l15;
        const u16* qp = Qb + ((size_t)(b * N_ + qrow)) * DK_ + h * HK_ + lg * 8;
        aq[0] = *reinterpret_cast<const short8*>(qp);
        aq[1] = *reinterpret_cast<const short8*>(qp + 32);
    }

    f32x4 o[4] = {};
    float m_[4], l_[4];
    #pragma unroll
    for (int j = 0; j < 4; ++j) { m_[j] = -1e30f; l_[j] = 0.0f; }

    for (int kt = 0; kt < N_ / 64; ++kt) {
        __syncthreads();
        #pragma unroll
        for (int i = 0; i < 2; ++i) {
            const int ob = (wave * 2 + i) * 1024;
            const int o_ = ob + lane * 16;
            const int row = o_ >> 7;
            const int inner = (o_ & 127) ^ ((row & 7) << 4);
            gload16((const char*)Kb +
                        ((size_t)(b * N_ + kt * 64 + row) * DK_ + h * HK_) * 2 + inner,
                    (char*)Ks + ob);
            gload16((const char*)Vt +
                        (((size_t)(b * NH_ + h) * HK_ + row) * N_ + kt * 64) * 2 + inner,
                    (char*)Vs + ob);
        }
        __syncthreads();

        // S = Q K^T (Q pre-scaled -> S already in log2 domain)
        f32x4 s[4] = {};
        #pragma unroll
        for (int ks = 0; ks < 2; ++ks) {
            const int kb2 = ks * 32 + lg * 8;
            #pragma unroll
            for (int t = 0; t < 4; ++t) {
                const int r = t * 16 + l15;
                const short8 bk = *reinterpret_cast<const short8*>(
                    &Ks[r * 64 + (kb2 ^ ((r & 7) << 3))]);
                s[t] = __builtin_amdgcn_mfma_f32_16x16x32_bf16(aq[ks], bk, s[t], 0, 0, 0);
            }
        }

        // deferred-max online softmax (common path: 4 shfl + exps only)
        float rmax[4], cm = -1e30f;
        #pragma unroll
        for (int jj = 0; jj < 4; ++jj) {
            rmax[jj] = fmaxf(fmaxf(s[0][jj], s[1][jj]), fmaxf(s[2][jj], s[3][jj]));
            cm = fmaxf(cm, rmax[jj] - m_[jj]);
        }
        cm = fmaxf(cm, __shfl_xor(cm, 1));
        cm = fmaxf(cm, __shfl_xor(cm, 2));
        cm = fmaxf(cm, __shfl_xor(cm, 4));
        cm = fmaxf(cm, __shfl_xor(cm, 8));
        if (cm > 8.0f) {   // rare: true max update + rescale
            #pragma unroll
            for (int jj = 0; jj < 4; ++jj) {
                float rm = rmax[jj];
                rm = fmaxf(rm, __shfl_xor(rm, 1));
                rm = fmaxf(rm, __shfl_xor(rm, 2));
                rm = fmaxf(rm, __shfl_xor(rm, 4));
                rm = fmaxf(rm, __shfl_xor(rm, 8));
                const float newm = fmaxf(m_[jj], rm);
                const float fac = exp2f_fast(m_[jj] - newm);
                m_[jj] = newm;
                l_[jj] *= fac;
                #pragma unroll
                for (int t = 0; t < 4; ++t) o[t][jj] *= fac;
            }
        }
        #pragma unroll
        for (int jj = 0; jj < 4; ++jj) {
            const float p0 = exp2f_fast(s[0][jj] - m_[jj]);
            const float p1 = exp2f_fast(s[1][jj] - m_[jj]);
            const float p2 = exp2f_fast(s[2][jj] - m_[jj]);
            const float p3 = exp2f_fast(s[3][jj] - m_[jj]);
            l_[jj] += (p0 + p1) + (p2 + p3);   // lane-local partial; reduced at end
            const int prow = wave * 16 + lg * 4 + jj;
            const int pb = prow * 64, sw = (prow & 7) << 3;
            Ps[pb + ((l15     ) ^ sw)] = f2bf_fast(p0);
            Ps[pb + ((l15 + 16) ^ sw)] = f2bf_fast(p1);
            Ps[pb + ((l15 + 32) ^ sw)] = f2bf_fast(p2);
            Ps[pb + ((l15 + 48) ^ sw)] = f2bf_fast(p3);
        }

        // O += P V (wave reads only its own 16 P rows)
        #pragma unroll
        for (int ks = 0; ks < 2; ++ks) {
            const int kb2 = ks * 32 + lg * 8;
            const int pr = wave * 16 + l15;
            const short8 ap = *reinterpret_cast<const short8*>(
                &Ps[pr * 64 + (kb2 ^ ((pr & 7) << 3))]);
            #pragma unroll
            for (int t = 0; t < 4; ++t) {
                const int dr = t * 16 + l15;
                const short8 bv = *reinterpret_cast<const short8*>(
                    &Vs[dr * 64 + (kb2 ^ ((dr & 7) << 3))]);
                o[t] = __builtin_amdgcn_mfma_f32_16x16x32_bf16(ap, bv, o[t], 0, 0, 0);
            }
        }
    }

    #pragma unroll
    for (int jj = 0; jj < 4; ++jj) {
        float rs = l_[jj];
        rs += __shfl_xor(rs, 1);
        rs += __shfl_xor(rs, 2);
        rs += __shfl_xor(rs, 4);
        rs += __shfl_xor(rs, 8);
        const float inv = 1.0f / rs;
        const size_t row = (size_t)b * N_ + qt * 64 + wave * 16 + lg * 4 + jj;
        #pragma unroll
        for (int t = 0; t < 4; ++t)
            att[row * (2 * DK_) + h * HK_ + t * 16 + l15] = f2bf_fast(o[t][jj] * inv);
    }
}

// ---------------------------------------------------------------------------
// Feature branch: S_f[kd,qd] = sum_n K[n,kd] * Qs[n,qd]  (MFMA, split over n)
// partials[split][bh][64][64] fp32
// ---------------------------------------------------------------------------
__global__ __launch_bounds__(256) void featS_mfma(
    const u16* __restrict__ Kb, const u16* __restrict__ Qb,
    float* __restrict__ partials)
{
    __shared__ u16 KsT[64 * 64];   // [kd][n], XOR-swizzled
    __shared__ u16 QsT[64 * 64];   // [qd][n], XOR-swizzled
    const int tid = threadIdx.x;
    const int lane = tid & 63, wave = tid >> 6;
    const int l15 = lane & 15, lg = lane >> 4;
    const int ns = blockIdx.x, h = blockIdx.y, b = blockIdx.z;
    const size_t hbase = (size_t)b * N_ * DK_ + (size_t)h * HK_;

    f32x4 acc[4] = {};
    for (int c = 0; c < 4; ++c) {
        const int n0 = ns * 256 + c * 64;
        __syncthreads();
        #pragma unroll
        for (int it = 0; it < 2; ++it) {
            const int idx = tid + it * 256;
            const int n = idx >> 3, d0 = (idx & 7) * 8;
            const u16x8 kv = *reinterpret_cast<const u16x8*>(
                &Kb[hbase + (size_t)(n0 + n) * DK_ + d0]);
            const u16x8 qv = *reinterpret_cast<const u16x8*>(
                &Qb[hbase + (size_t)(n0 + n) * DK_ + d0]);
            #pragma unroll
            for (int j = 0; j < 8; ++j) {
                const int r = d0 + j;
                const int cidx = n ^ ((r & 7) << 3);
                KsT[r * 64 + cidx] = kv[j];
                QsT[r * 64 + cidx] = qv[j];
            }
        }
        __syncthreads();
        #pragma unroll
        for (int ks = 0; ks < 2; ++ks) {
            const int kb2 = ks * 32 + lg * 8;
            const int ar = wave * 16 + l15;
            const short8 aK = *reinterpret_cast<const short8*>(
                &KsT[ar * 64 + (kb2 ^ ((ar & 7) << 3))]);
            #pragma unroll
            for (int ni = 0; ni < 4; ++ni) {
                const int br = ni * 16 + l15;
                const short8 bQ = *reinterpret_cast<const short8*>(
                    &QsT[br * 64 + (kb2 ^ ((br & 7) << 3))]);
                acc[ni] = __builtin_amdgcn_mfma_f32_16x16x32_bf16(aK, bQ, acc[ni], 0, 0, 0);
            }
        }
    }
    const int bh = b * NH_ + h;
    #pragma unroll
    for (int ni = 0; ni < 4; ++ni)
        #pragma unroll
        for (int jj = 0; jj < 4; ++jj) {
            const int row = wave * 16 + lg * 4 + jj;
            partials[(((size_t)ns * 32 + bh) * 64 + row) * 64 + ni * 16 + l15] =
                acc[ni][jj];
        }
}

// sum partials, softmax over qd, write distfT[bh][qd][kd] bf16
__global__ __launch_bounds__(256) void featSM_kernel(
    const float* __restrict__ partials, u16* __restrict__ distfT)
{
    const int bh = blockIdx.x, tid = threadIdx.x;
    const int r = tid >> 2, qq = tid & 3;   // row kd=r, cols qq*16..+15
    float v[16];
    #pragma unroll
    for (int j = 0; j < 16; ++j) v[j] = 0.0f;
    for (int s = 0; s < 8; ++s) {
        const float4* pp = reinterpret_cast<const float4*>(
            &partials[(((size_t)s * 32 + bh) * 64 + r) * 64 + qq * 16]);
        #pragma unroll
        for (int j4 = 0; j4 < 4; ++j4) {
            const float4 a = pp[j4];
            v[j4 * 4 + 0] += a.x; v[j4 * 4 + 1] += a.y;
            v[j4 * 4 + 2] += a.z; v[j4 * 4 + 3] += a.w;
        }
    }
    float m = v[0];
    #pragma unroll
    for (int j = 1; j < 16; ++j) m = fmaxf(m, v[j]);
    m = fmaxf(m, __shfl_xor(m, 1));
    m = fmaxf(m, __shfl_xor(m, 2));
    float sum = 0.0f;
    #pragma unroll
    for (int j = 0; j < 16; ++j) { v[j] = exp2f_fast(v[j] - m); sum += v[j]; }
    sum += __shfl_xor(sum, 1);
    sum += __shfl_xor(sum, 2);
    const float inv = 1.0f / sum;
    #pragma unroll
    for (int j = 0; j < 16; ++j)
        distfT[(size_t)bh * 4096 + (qq * 16 + j) * 64 + r] = f2bf_fast(v[j] * inv);
}

// att_f[n,q] = sum_d V[n,d] * distf[d,q] -> att[:, 512+h*64+q] (MFMA)
__global__ __launch_bounds__(256) void featAV_mfma(
    const u16* __restrict__ V, const u16* __restrict__ distfT,
    u16* __restrict__ att)
{
    __shared__ u16 Bs[64 * 64];   // distfT[q][d], XOR-swizzled
    __shared__ u16 As[64 * 64];   // V rows
    const int tid = threadIdx.x;
    const int lane = tid & 63, wave = tid >> 6;
    const int l15 = lane & 15, lg = lane >> 4;
    const int ns = blockIdx.x, h = blockIdx.y, b = blockIdx.z;
    const int bh = b * NH_ + h;

    #pragma unroll
    for (int it = 0; it < 2; ++it) {
        const int idx = tid + it * 256;
        const int r = idx >> 3, c0 = (idx & 7) * 8;
        const u16x8 dv = *reinterpret_cast<const u16x8*>(
            &distfT[(size_t)bh * 4096 + r * 64 + c0]);
        *reinterpret_cast<u16x8*>(&Bs[r * 64 + (c0 ^ ((r & 7) << 3))]) = dv;
    }

    for (int c = 0; c < 4; ++c) {
        const int n0 = ns * 256 + c * 64;
        __syncthreads();
        #pragma unroll
        for (int i = 0; i < 2; ++i) {
            const int ob = (wave * 2 + i) * 1024;
            const int o_ = ob + lane * 16;
            const int row = o_ >> 7;
            const int inner = (o_ & 127) ^ ((row & 7) << 4);
            gload16((const char*)V + ((size_t)(b * N_ + n0 + row) * DK_ + h * HK_) * 2 + inner,
                    (char*)As + ob);
        }
        __syncthreads();
        f32x4 acc[4] = {};
        #pragma unroll
        for (int ks = 0; ks < 2; ++ks) {
            const int kb2 = ks * 32 + lg * 8;
            const int ar = wave * 16 + l15;
            const short8 av = *reinterpret_cast<const short8*>(
                &As[ar * 64 + (kb2 ^ ((ar & 7) << 3))]);
            #pragma unroll
            for (int ni = 0; ni < 4; ++ni) {
                const int br = ni * 16 + l15;
                const short8 bd = *reinterpret_cast<const short8*>(
                    &Bs[br * 64 + (kb2 ^ ((br & 7) << 3))]);
                acc[ni] = __builtin_amdgcn_mfma_f32_16x16x32_bf16(av, bd, acc[ni], 0, 0, 0);
            }
        }
        #pragma unroll
        for (int ni = 0; ni < 4; ++ni)
            #pragma unroll
            for (int jj = 0; jj < 4; ++jj)
                att[((size_t)b * N_ + n0 + wave * 16 + lg * 4 + jj) * (2 * DK_)
                    + 512 + h * HK_ + ni * 16 + l15] = f2bf_fast(acc[ni][jj]);
    }
}

// ---------------------------------------------------------------------------
__global__ __launch_bounds__(256) void ln_kernel(
    const float* __restrict__ fc, const float* __restrict__ gamma,
    const float* __restrict__ beta, float* __restrict__ out)
{
    __shared__ float red[8];
    const int row = blockIdx.x, tid = threadIdx.x;
    const int c = tid * 2;
    const float2 v = *reinterpret_cast<const float2*>(&fc[(size_t)row * D_ + c]);
    float s = v.x + v.y;
    float sq = v.x * v.x + v.y * v.y;
    #pragma unroll
    for (int off = 32; off >= 1; off >>= 1) {
        s  += __shfl_xor(s, off);
        sq += __shfl_xor(sq, off);
    }
    const int lane = tid & 63, w = tid >> 6;
    if (lane == 0) { red[w] = s; red[4 + w] = sq; }
    __syncthreads();
    s  = red[0] + red[1] + red[2] + red[3];
    sq = red[4] + red[5] + red[6] + red[7];
    const float mu = s * (1.0f / D_);
    const float var = sq * (1.0f / D_) - mu * mu;
    const float rstd = rsqrtf(var + LN_EPS_);
    float2 o;
    o.x = (v.x - mu) * rstd * gamma[c] + beta[c];
    o.y = (v.y - mu) * rstd * gamma[c + 1] + beta[c + 1];
    *reinterpret_cast<float2*>(&out[(size_t)row * D_ + c]) = o;
}

// ---------------------------------------------------------------------------
extern "C" void kernel_launch(void* const* d_in, const int* in_sizes, int n_in,
                              void* d_out, int out_size, void* d_ws, size_t ws_size,
                              hipStream_t stream)
{
    (void)in_sizes; (void)n_in; (void)out_size; (void)ws_size;
    const float* x     = (const float*)d_in[0];
    const float* Wq    = (const float*)d_in[1];
    const float* Wk    = (const float*)d_in[2];
    const float* Wv    = (const float*)d_in[3];
    const float* Wf    = (const float*)d_in[4];
    const float* bf    = (const float*)d_in[5];
    const float* gamma = (const float*)d_in[6];
    const float* beta  = (const float*)d_in[7];
    float* out = (float*)d_out;

    char* w = (char*)d_ws;
    const size_t SZE = (size_t)B_ * N_ * DK_;            // 4,194,304 elems
    u16* xb     = (u16*)w;   w += SZE * 2;
    u16* wqkvT  = (u16*)w;   w += (size_t)1536 * 512 * 2;
    u16* wfT    = (u16*)w;   w += (size_t)512 * 1024 * 2;
    u16* qb     = (u16*)w;   w += SZE * 2;
    u16* kb     = (u16*)w;   w += SZE * 2;
    u16* vb     = (u16*)w;   w += SZE * 2;
    u16* vt     = (u16*)w;   w += SZE * 2;
    u16* attb   = (u16*)w;   w += SZE * 2 * 2;
    float* partials = (float*)w; w += (size_t)8 * 32 * 4096 * 4;   // 4 MB
    u16* distfT = (u16*)w;   w += (size_t)32 * 4096 * 2;
    float* fcout = (float*)w;

    const dim3 blk(256);
    const int M = B_ * N_;

    conv_bf16_kernel<<<dim3((B_ * N_ * D_) / 2048), blk, 0, stream>>>(x, xb, B_ * N_ * D_);
    tc_kernel<<<dim3(16, 16), blk, 0, stream>>>(Wq, wqkvT, 512, 512);
    tc_kernel<<<dim3(16, 16), blk, 0, stream>>>(Wk, wqkvT + (size_t)512 * 512, 512, 512);
    tc_kernel<<<dim3(16, 16), blk, 0, stream>>>(Wv, wqkvT + (size_t)1024 * 512, 512, 512);
    tc_kernel<<<dim3(16, 32), blk, 0, stream>>>(Wf, wfT, 1024, 512);

    // fused QKV projection: [8192,512] @ [512,1536]; q written pre-scaled
    gemm_bf16<128, 128, 1><<<dim3(768), blk, 0, stream>>>(
        xb, wqkvT, nullptr, qb, kb, vb, M, 1536, 512, nullptr, nullptr);

    vtrans_kernel<<<dim3(N_ / 64, NH_, B_), blk, 0, stream>>>(vb, vt);

    flash_bf16_kernel<<<dim3(1024), blk, 0, stream>>>(qb, kb, vt, attb);

    featS_mfma<<<dim3(8, NH_, B_), blk, 0, stream>>>(kb, qb, partials);
    featSM_kernel<<<dim3(32), blk, 0, stream>>>(partials, distfT);
    featAV_mfma<<<dim3(8, NH_, B_), blk, 0, stream>>>(vb, distfT, attb);

    // FC + bias + relu + resid (fp32 out)
    gemm_bf16<64, 128, 2><<<dim3(512), blk, 0, stream>>>(
        attb, wfT, fcout, nullptr, nullptr, nullptr, M, D_, 2 * DK_, bf, x);

    ln_kernel<<<dim3(M), blk, 0, stream>>>(fcout, gamma, beta, out);
}